// Round 4
// baseline (815.180 us; speedup 1.0000x reference)
//
#include <hip/hip_runtime.h>
#include <hip/hip_bf16.h>

// Problem constants
#define BB 4096
#define TT 8
#define CHIN 2048
#define CC 1024
#define NN 512
#define KK 5
#define KN (KK*NN)   // 2560

typedef __bf16 bf16x8 __attribute__((ext_vector_type(8)));
typedef float  f32x4  __attribute__((ext_vector_type(4)));

#define TM 128
#define TN 128
#define BK 64

__device__ __forceinline__ void gload_lds16(const __hip_bfloat16* g, __hip_bfloat16* l) {
    __builtin_amdgcn_global_load_lds(
        (__attribute__((address_space(1))) void*)const_cast<__hip_bfloat16*>(g),
        (__attribute__((address_space(3))) void*)l,
        16, 0, 0);
}

// C[m][n] = sum_k A[m][k] * BT[n][k]  (+ bias_col[n] + bias_row[m]), fp32 out.
// M%128==0, N%128==0, K%64==0 required (all shapes here satisfy).
__global__ __launch_bounds__(256) void gemm_abt(
    const __hip_bfloat16* __restrict__ A, int lda,
    const __hip_bfloat16* __restrict__ BT, int ldb,
    float* __restrict__ Cmat, int ldc,
    int M, int N, int Kdim,
    const float* __restrict__ bias_col,
    const float* __restrict__ bias_row)
{
    __shared__ __align__(16) __hip_bfloat16 As[TM * BK];
    __shared__ __align__(16) __hip_bfloat16 Bs[TN * BK];

    const int tid  = threadIdx.x;
    const int wave = tid >> 6;
    const int lane = tid & 63;
    const int wm = (wave >> 1) * 64;   // wave row offset in tile
    const int wn = (wave & 1) * 64;    // wave col offset in tile
    const int bm = blockIdx.y * TM;
    const int bn = blockIdx.x * TN;

    // staging: thread t stages 8 bf16 (16B): row = t/8, colgrp = (t%8)*8
    const int srow = tid >> 3;
    const int scol = (tid & 7) * 8;

    const __hip_bfloat16* Ag = A  + (size_t)bm * lda;
    const __hip_bfloat16* Bg = BT + (size_t)bn * ldb;

    f32x4 acc[4][4];
    #pragma unroll
    for (int i = 0; i < 4; ++i)
        #pragma unroll
        for (int j = 0; j < 4; ++j)
            acc[i][j] = {0.f, 0.f, 0.f, 0.f};

    for (int k0 = 0; k0 < Kdim; k0 += BK) {
        #pragma unroll
        for (int r = 0; r < 4; ++r) {
            int row = srow + r * 32;
            gload_lds16(Ag + (size_t)row * lda + k0 + scol, &As[row * BK + scol]);
        }
        #pragma unroll
        for (int r = 0; r < 4; ++r) {
            int row = srow + r * 32;
            gload_lds16(Bg + (size_t)row * ldb + k0 + scol, &Bs[row * BK + scol]);
        }
        __syncthreads();

        #pragma unroll
        for (int kk = 0; kk < BK; kk += 32) {
            const int koff = kk + (lane >> 4) * 8;   // k = quad*8 + j
            const int arow = wm + (lane & 15);
            const int brow = wn + (lane & 15);
            bf16x8 aFrag[4], bFrag[4];
            #pragma unroll
            for (int i = 0; i < 4; ++i)
                aFrag[i] = *(const bf16x8*)(&As[(arow + i * 16) * BK + koff]);
            #pragma unroll
            for (int j = 0; j < 4; ++j)
                bFrag[j] = *(const bf16x8*)(&Bs[(brow + j * 16) * BK + koff]);
            #pragma unroll
            for (int i = 0; i < 4; ++i)
                #pragma unroll
                for (int j = 0; j < 4; ++j)
                    acc[i][j] = __builtin_amdgcn_mfma_f32_16x16x32_bf16(
                        aFrag[i], bFrag[j], acc[i][j], 0, 0, 0);
        }
        __syncthreads();
    }

    // epilogue: C/D mapping (verified m89): col = lane&15, row = (lane>>4)*4 + reg
    const int quad = lane >> 4;
    #pragma unroll
    for (int i = 0; i < 4; ++i) {
        #pragma unroll
        for (int j = 0; j < 4; ++j) {
            const int col = bn + wn + j * 16 + (lane & 15);
            float bc = bias_col ? bias_col[col] : 0.f;
            #pragma unroll
            for (int r = 0; r < 4; ++r) {
                const int row = bm + wm + i * 16 + quad * 4 + r;
                float br = bias_row ? bias_row[row] : 0.f;
                Cmat[(size_t)row * ldc + col] = acc[i][j][r] + bc + br;
            }
        }
    }
}

// flat fp32 -> bf16 cast, 4 elems/thread. n % 1024 == 0.
__global__ __launch_bounds__(256) void cast_f32_bf16(const float* __restrict__ in,
                                                     __hip_bfloat16* __restrict__ out, int n)
{
    const int idx = (blockIdx.x * 256 + threadIdx.x) * 4;
    if (idx >= n) return;
    const float4 vv = *(const float4*)(in + idx);
    union { __hip_bfloat16 h[4]; unsigned long long u; } pk;
    pk.h[0] = (__hip_bfloat16)vv.x; pk.h[1] = (__hip_bfloat16)vv.y;
    pk.h[2] = (__hip_bfloat16)vv.z; pk.h[3] = (__hip_bfloat16)vv.w;
    *(unsigned long long*)(out + idx) = pk.u;
}

// xb[b][i] = (bf16) x[b][T-1][i]
__global__ __launch_bounds__(256) void cast_xlast(const float* __restrict__ x,
                                                  __hip_bfloat16* __restrict__ xb)
{
    const int b = blockIdx.y;
    const int i = (blockIdx.x * 256 + threadIdx.x) * 4;
    const float4 vv = *(const float4*)(x + ((size_t)b * TT + TT - 1) * CHIN + i);
    union { __hip_bfloat16 h[4]; unsigned long long u; } pk;
    pk.h[0] = (__hip_bfloat16)vv.x; pk.h[1] = (__hip_bfloat16)vv.y;
    pk.h[2] = (__hip_bfloat16)vv.z; pk.h[3] = (__hip_bfloat16)vv.w;
    *(unsigned long long*)(xb + (size_t)b * CHIN + i) = pk.u;
}

// static[k][i][n] (fp32) -> staticT[k*NN+n][i] (bf16)
__global__ void transpose_static(const float* __restrict__ st,
                                 __hip_bfloat16* __restrict__ stT)
{
    __shared__ float tile[32][33];
    const int k  = blockIdx.z;
    const int i0 = blockIdx.x * 32;   // CH_IN
    const int n0 = blockIdx.y * 32;   // N
    const int tx = threadIdx.x, ty = threadIdx.y;   // 32 x 8
    #pragma unroll
    for (int r = 0; r < 32; r += 8)
        tile[ty + r][tx] = st[((size_t)k * CHIN + i0 + ty + r) * NN + n0 + tx];
    __syncthreads();
    #pragma unroll
    for (int r = 0; r < 32; r += 8)
        stT[((size_t)k * NN + n0 + ty + r) * CHIN + i0 + tx] = (__hip_bfloat16)tile[tx][ty + r];
}

// L2-normalize each row (cols fp32) -> bf16 out. norm = max(||row||, 1e-8)
__global__ __launch_bounds__(256) void rownorm(const float* __restrict__ in,
                                               __hip_bfloat16* __restrict__ out,
                                               int cols)
{
    const int row = blockIdx.x;
    const float* p = in + (size_t)row * cols;
    float s = 0.f;
    for (int c = threadIdx.x; c < cols; c += 256) { float v = p[c]; s += v * v; }
    #pragma unroll
    for (int o = 32; o > 0; o >>= 1) s += __shfl_down(s, o, 64);
    __shared__ float red[4];
    if ((threadIdx.x & 63) == 0) red[threadIdx.x >> 6] = s;
    __syncthreads();
    const float tot = red[0] + red[1] + red[2] + red[3];
    const float inv = 1.f / fmaxf(sqrtf(tot), 1e-8f);
    for (int c = threadIdx.x; c < cols; c += 256)
        out[(size_t)row * cols + c] = (__hip_bfloat16)(p[c] * inv);
}

// g[kn] = sum_c Ww[c] * Ev2[c][kn]; also Ev2 fp32 -> bf16
__global__ __launch_bounds__(256) void prep_ev(const float* __restrict__ Ev2,
                                               const float* __restrict__ Ww,
                                               float* __restrict__ g,
                                               __hip_bfloat16* __restrict__ Ev2b)
{
    const int kn = blockIdx.x * 256 + threadIdx.x;  // < 2560
    float acc = 0.f;
    for (int c = 0; c < CC; ++c) {
        float v = Ev2[(size_t)c * KN + kn];
        acc += Ww[c] * v;
        Ev2b[(size_t)c * KN + kn] = (__hip_bfloat16)v;
    }
    g[kn] = acc;
}

// per (b,k): softmax over 512, fw = sigmoid(dot(w,g)+bw), u = w*fw (bf16)
__global__ __launch_bounds__(64) void softmax_u(const float* __restrict__ sim,
                                                const float* __restrict__ g,
                                                const float* __restrict__ bw,
                                                __hip_bfloat16* __restrict__ u)
{
    const int bk = blockIdx.x;
    const int b = bk / KK, k = bk % KK;
    const float* sp = sim + (size_t)b * KN + k * NN;
    const float* gp = g + k * NN;
    const int lane = threadIdx.x;

    float vals[8];
    float m = -1e30f;
    #pragma unroll
    for (int j = 0; j < 8; ++j) { vals[j] = sp[lane + 64 * j]; m = fmaxf(m, vals[j]); }
    #pragma unroll
    for (int o = 32; o > 0; o >>= 1) m = fmaxf(m, __shfl_xor(m, o, 64));
    float sum = 0.f;
    #pragma unroll
    for (int j = 0; j < 8; ++j) { vals[j] = expf(vals[j] - m); sum += vals[j]; }
    #pragma unroll
    for (int o = 32; o > 0; o >>= 1) sum += __shfl_xor(sum, o, 64);
    const float inv = 1.f / sum;
    float dot = 0.f;
    #pragma unroll
    for (int j = 0; j < 8; ++j) { vals[j] *= inv; dot += vals[j] * gp[lane + 64 * j]; }
    #pragma unroll
    for (int o = 32; o > 0; o >>= 1) dot += __shfl_xor(dot, o, 64);
    const float fw = 1.f / (1.f + expf(-(dot + bw[0])));
    __hip_bfloat16* up = u + (size_t)b * KN + k * NN;
    #pragma unroll
    for (int j = 0; j < 8; ++j) up[lane + 64 * j] = (__hip_bfloat16)(vals[j] * fw);
}

// out[b][kk] = bout[kk] + sum_c Wout[kk][c]*relu(v) + Wout[kk][C+c]*relu(fE)
// OUTPUT IS FLOAT32 (reference output dtype) — this was the round-2/3 bug.
__global__ __launch_bounds__(256) void final_out(const float* __restrict__ v,
                                                 const float* __restrict__ fE,
                                                 const float* __restrict__ Wout,
                                                 const float* __restrict__ bout,
                                                 float* __restrict__ out)
{
    const int b = blockIdx.x;
    float acc[KK] = {0.f, 0.f, 0.f, 0.f, 0.f};
    for (int c = threadIdx.x; c < CC; c += 256) {
        const float rv = fmaxf(v[(size_t)b * CC + c], 0.f);
        const float rf = fmaxf(fE[(size_t)b * CC + c], 0.f);
        #pragma unroll
        for (int kk = 0; kk < KK; ++kk)
            acc[kk] += Wout[kk * 2 * CC + c] * rv
                     + Wout[kk * 2 * CC + CC + c] * rf;
    }
    __shared__ float red[KK][4];
    const int lane = threadIdx.x & 63, wave = threadIdx.x >> 6;
    #pragma unroll
    for (int kk = 0; kk < KK; ++kk) {
        float s = acc[kk];
        #pragma unroll
        for (int o = 32; o > 0; o >>= 1) s += __shfl_down(s, o, 64);
        if (lane == 0) red[kk][wave] = s;
    }
    __syncthreads();
    if (threadIdx.x < KK) {
        float s = red[threadIdx.x][0] + red[threadIdx.x][1]
                + red[threadIdx.x][2] + red[threadIdx.x][3];
        out[(size_t)b * KK + threadIdx.x] = s + bout[threadIdx.x];
    }
}

extern "C" void kernel_launch(void* const* d_in, const int* in_sizes, int n_in,
                              void* d_out, int out_size, void* d_ws, size_t ws_size,
                              hipStream_t stream)
{
    const float* x    = (const float*)d_in[0];
    const float* stat = (const float*)d_in[1];
    const float* Wk   = (const float*)d_in[2];
    const float* bk   = (const float*)d_in[3];
    const float* Wv   = (const float*)d_in[4];
    const float* bv   = (const float*)d_in[5];
    const float* WEk  = (const float*)d_in[6];
    const float* bEk  = (const float*)d_in[7];
    const float* WEv  = (const float*)d_in[8];
    const float* bEv  = (const float*)d_in[9];
    const float* Ww   = (const float*)d_in[10];
    const float* bw   = (const float*)d_in[11];
    const float* Wout = (const float*)d_in[12];
    const float* bout = (const float*)d_in[13];
    float* out = (float*)d_out;   // fp32 output per reference dtype
    char* ws = (char*)d_ws;

    // workspace layout (bytes), ~126 MB total, with aliasing:
    //   [0,10.49M)      staticT bf16 (dead after step 4)  \ u bf16 [0,20.97M) from step 10
    //   [10.49,20.97M)  EkT fp32     (dead after step 3)  /
    //   [20.97,31.46M)  Ev2 fp32     (dead after step 5)
    //   [31.46,36.70M)  EknT bf16    (dead after step 9)
    //   [36.70,41.94M)  Ev2b bf16
    //   [41.94M,+10K)   g fp32
    //   [41.96,58.74M)  kpre fp32 (written step 6) | WEkb,WEvb bf16 (dead after step 4) ; then fE
    //   [58.74,75.51M)  v fp32
    //   [75.51,83.90M)  kn bf16
    //   [83.90,125.85M) sim fp32 (written step 9) | Wkb,Wvb,xb bf16 (dead after step 8)
    __hip_bfloat16* staticT = (__hip_bfloat16*)(ws + 0);
    float*          EkT     = (float*)(ws + 10485760);
    __hip_bfloat16* u       = (__hip_bfloat16*)(ws + 0);
    float*          Ev2     = (float*)(ws + 20971520);
    __hip_bfloat16* EknT    = (__hip_bfloat16*)(ws + 31457280);
    __hip_bfloat16* Ev2b    = (__hip_bfloat16*)(ws + 36700160);
    float*          g       = (float*)(ws + 41943040);
    float*          kpre    = (float*)(ws + 41959424);
    __hip_bfloat16* WEkb    = (__hip_bfloat16*)(ws + 41959424);            // alias kpre
    __hip_bfloat16* WEvb    = (__hip_bfloat16*)(ws + 41959424 + 4194304);  // alias kpre
    float*          fE      = kpre;
    float*          v       = (float*)(ws + 58736640);
    __hip_bfloat16* kn      = (__hip_bfloat16*)(ws + 75513856);
    float*          sim     = (float*)(ws + 83902464);
    __hip_bfloat16* Wkb     = (__hip_bfloat16*)(ws + 83902464);             // alias sim
    __hip_bfloat16* Wvb     = (__hip_bfloat16*)(ws + 83902464 + 4194304);   // alias sim
    __hip_bfloat16* xb      = (__hip_bfloat16*)(ws + 83902464 + 8388608);   // alias sim

    const int WN = CC * CHIN;  // 2,097,152 elems per weight matrix

    // 0. casts (fp32 inputs -> bf16 GEMM operands)
    cast_f32_bf16<<<WN / 1024, 256, 0, stream>>>(WEk, WEkb, WN);
    cast_f32_bf16<<<WN / 1024, 256, 0, stream>>>(WEv, WEvb, WN);
    cast_f32_bf16<<<WN / 1024, 256, 0, stream>>>(Wk, Wkb, WN);
    cast_f32_bf16<<<WN / 1024, 256, 0, stream>>>(Wv, Wvb, WN);
    cast_xlast<<<dim3(CHIN / 1024, BB), 256, 0, stream>>>(x, xb);
    // 1. staticT[k*N+n][i] = (bf16) static[k][i][n]
    transpose_static<<<dim3(CHIN / 32, NN / 32, KK), dim3(32, 8), 0, stream>>>(stat, staticT);
    // 2. EkT[kn][c] = sum_i staticT[kn][i]*WEk[c][i] + bEk[c]
    gemm_abt<<<dim3(CC / TN, KN / TM), 256, 0, stream>>>(
        staticT, CHIN, WEkb, CHIN, EkT, CC, KN, CC, CHIN, bEk, nullptr);
    // 3. EknT = rownormalize(EkT) (norm over c)
    rownorm<<<KN, 256, 0, stream>>>(EkT, EknT, CC);
    // 4. Ev2[c][kn] = sum_i WEv[c][i]*staticT[kn][i] + bEv[c] (bias per row)
    gemm_abt<<<dim3(KN / TN, CC / TM), 256, 0, stream>>>(
        WEvb, CHIN, staticT, CHIN, Ev2, KN, CC, KN, CHIN, nullptr, bEv);
    // 5. g[kn] = Ww . Ev2[:,kn]; Ev2 -> bf16
    prep_ev<<<KN / 256, 256, 0, stream>>>(Ev2, Ww, g, Ev2b);
    // 6. kpre = x_last @ Wk^T + bk
    gemm_abt<<<dim3(CC / TN, BB / TM), 256, 0, stream>>>(
        xb, CHIN, Wkb, CHIN, kpre, CC, BB, CC, CHIN, bk, nullptr);
    // 7. kn = rownormalize(kpre)
    rownorm<<<BB, 256, 0, stream>>>(kpre, kn, CC);
    // 8. v = x_last @ Wv^T + bv
    gemm_abt<<<dim3(CC / TN, BB / TM), 256, 0, stream>>>(
        xb, CHIN, Wvb, CHIN, v, CC, BB, CC, CHIN, bv, nullptr);
    // 9. sim = kn @ EknT^T
    gemm_abt<<<dim3(KN / TN, BB / TM), 256, 0, stream>>>(
        kn, CC, EknT, CC, sim, KN, BB, KN, CC, nullptr, nullptr);
    // 10. softmax + fw + u
    softmax_u<<<BB * KK, 64, 0, stream>>>(sim, g, bw, u);
    // 11. fE = u @ Ev2b^T
    gemm_abt<<<dim3(CC / TN, BB / TM), 256, 0, stream>>>(
        u, KN, Ev2b, KN, fE, CC, BB, CC, KN, nullptr, nullptr);
    // 12. out = relu([v, fE]) @ Wout^T + bout
    final_out<<<BB, 256, 0, stream>>>(v, fE, Wout, bout, out);
}

// Round 5
// 631.276 us; speedup vs baseline: 1.2913x; 1.2913x over previous
//
#include <hip/hip_runtime.h>
#include <hip/hip_bf16.h>

// Problem constants
#define BB 4096
#define TT 8
#define CHIN 2048
#define CC 1024
#define NN 512
#define KK 5
#define KN (KK*NN)   // 2560

typedef __bf16 bf16x8 __attribute__((ext_vector_type(8)));
typedef float  f32x4  __attribute__((ext_vector_type(4)));

#define TM 128
#define TN 128
#define BK 64

__device__ __forceinline__ void gload_lds16(const __hip_bfloat16* g, __hip_bfloat16* l) {
    __builtin_amdgcn_global_load_lds(
        (__attribute__((address_space(1))) void*)const_cast<__hip_bfloat16*>(g),
        (__attribute__((address_space(3))) void*)l,
        16, 0, 0);
}

// C[m][n] = sum_k A[m][k] * BT[n][k]  (+ bias_col[n]), fp32 out.
// M%128==0, N%128==0, K%64==0 required.
__global__ __launch_bounds__(256) void gemm_abt(
    const __hip_bfloat16* __restrict__ A, int lda,
    const __hip_bfloat16* __restrict__ BT, int ldb,
    float* __restrict__ Cmat, int ldc,
    int M, int N, int Kdim,
    const float* __restrict__ bias_col)
{
    __shared__ __align__(16) __hip_bfloat16 As[TM * BK];
    __shared__ __align__(16) __hip_bfloat16 Bs[TN * BK];

    const int tid  = threadIdx.x;
    const int wave = tid >> 6;
    const int lane = tid & 63;
    const int wm = (wave >> 1) * 64;
    const int wn = (wave & 1) * 64;
    const int bm = blockIdx.y * TM;
    const int bn = blockIdx.x * TN;

    const int srow = tid >> 3;
    const int scol = (tid & 7) * 8;

    const __hip_bfloat16* Ag = A  + (size_t)bm * lda;
    const __hip_bfloat16* Bg = BT + (size_t)bn * ldb;

    f32x4 acc[4][4];
    #pragma unroll
    for (int i = 0; i < 4; ++i)
        #pragma unroll
        for (int j = 0; j < 4; ++j)
            acc[i][j] = {0.f, 0.f, 0.f, 0.f};

    for (int k0 = 0; k0 < Kdim; k0 += BK) {
        #pragma unroll
        for (int r = 0; r < 4; ++r) {
            int row = srow + r * 32;
            gload_lds16(Ag + (size_t)row * lda + k0 + scol, &As[row * BK + scol]);
        }
        #pragma unroll
        for (int r = 0; r < 4; ++r) {
            int row = srow + r * 32;
            gload_lds16(Bg + (size_t)row * ldb + k0 + scol, &Bs[row * BK + scol]);
        }
        __syncthreads();

        #pragma unroll
        for (int kk = 0; kk < BK; kk += 32) {
            const int koff = kk + (lane >> 4) * 8;
            const int arow = wm + (lane & 15);
            const int brow = wn + (lane & 15);
            bf16x8 aFrag[4], bFrag[4];
            #pragma unroll
            for (int i = 0; i < 4; ++i)
                aFrag[i] = *(const bf16x8*)(&As[(arow + i * 16) * BK + koff]);
            #pragma unroll
            for (int j = 0; j < 4; ++j)
                bFrag[j] = *(const bf16x8*)(&Bs[(brow + j * 16) * BK + koff]);
            #pragma unroll
            for (int i = 0; i < 4; ++i)
                #pragma unroll
                for (int j = 0; j < 4; ++j)
                    acc[i][j] = __builtin_amdgcn_mfma_f32_16x16x32_bf16(
                        aFrag[i], bFrag[j], acc[i][j], 0, 0, 0);
        }
        __syncthreads();
    }

    // C/D mapping: col = lane&15, row = (lane>>4)*4 + reg
    const int quad = lane >> 4;
    #pragma unroll
    for (int i = 0; i < 4; ++i) {
        #pragma unroll
        for (int j = 0; j < 4; ++j) {
            const int col = bn + wn + j * 16 + (lane & 15);
            const float bc = bias_col ? bias_col[col] : 0.f;
            #pragma unroll
            for (int r = 0; r < 4; ++r) {
                const int row = bm + wm + i * 16 + quad * 4 + r;
                Cmat[(size_t)row * ldc + col] = acc[i][j][r] + bc;
            }
        }
    }
}

// flat fp32 -> bf16 cast, 4 elems/thread. n % 1024 == 0.
__global__ __launch_bounds__(256) void cast_f32_bf16(const float* __restrict__ in,
                                                     __hip_bfloat16* __restrict__ out, int n)
{
    const int idx = (blockIdx.x * 256 + threadIdx.x) * 4;
    if (idx >= n) return;
    const float4 vv = *(const float4*)(in + idx);
    union { __hip_bfloat16 h[4]; unsigned long long u; } pk;
    pk.h[0] = (__hip_bfloat16)vv.x; pk.h[1] = (__hip_bfloat16)vv.y;
    pk.h[2] = (__hip_bfloat16)vv.z; pk.h[3] = (__hip_bfloat16)vv.w;
    *(unsigned long long*)(out + idx) = pk.u;
}

// xb[b][i] = (bf16) x[b][T-1][i]
__global__ __launch_bounds__(256) void cast_xlast(const float* __restrict__ x,
                                                  __hip_bfloat16* __restrict__ xb)
{
    const int b = blockIdx.y;
    const int i = (blockIdx.x * 256 + threadIdx.x) * 4;
    const float4 vv = *(const float4*)(x + ((size_t)b * TT + TT - 1) * CHIN + i);
    union { __hip_bfloat16 h[4]; unsigned long long u; } pk;
    pk.h[0] = (__hip_bfloat16)vv.x; pk.h[1] = (__hip_bfloat16)vv.y;
    pk.h[2] = (__hip_bfloat16)vv.z; pk.h[3] = (__hip_bfloat16)vv.w;
    *(unsigned long long*)(xb + (size_t)b * CHIN + i) = pk.u;
}

// concat two fp32 vectors of length CC into out[0:CC]=a, out[CC:2CC]=b
__global__ __launch_bounds__(256) void concat_bias(const float* __restrict__ a,
                                                   const float* __restrict__ b,
                                                   float* __restrict__ out)
{
    const int i = blockIdx.x * 256 + threadIdx.x;  // < 2CC
    out[i] = (i < CC) ? a[i] : b[i - CC];
}

// static[k][i][n] (fp32) -> staticT[k*NN+n][i] (bf16)
__global__ void transpose_static(const float* __restrict__ st,
                                 __hip_bfloat16* __restrict__ stT)
{
    __shared__ float tile[32][33];
    const int k  = blockIdx.z;
    const int i0 = blockIdx.x * 32;
    const int n0 = blockIdx.y * 32;
    const int tx = threadIdx.x, ty = threadIdx.y;   // 32 x 8
    #pragma unroll
    for (int r = 0; r < 32; r += 8)
        tile[ty + r][tx] = st[((size_t)k * CHIN + i0 + ty + r) * NN + n0 + tx];
    __syncthreads();
    #pragma unroll
    for (int r = 0; r < 32; r += 8)
        stT[((size_t)k * NN + n0 + ty + r) * CHIN + i0 + tx] = (__hip_bfloat16)tile[tx][ty + r];
}

// bf16 [KN][CC] -> bf16 [CC][KN] transpose
__global__ void transpose_bf16(const __hip_bfloat16* __restrict__ in,
                               __hip_bfloat16* __restrict__ outp)
{
    __shared__ __hip_bfloat16 tile[32][33];
    const int c0  = blockIdx.x * 32;   // CC
    const int kn0 = blockIdx.y * 32;   // KN
    const int tx = threadIdx.x, ty = threadIdx.y;   // 32 x 8
    #pragma unroll
    for (int r = 0; r < 32; r += 8)
        tile[ty + r][tx] = in[(size_t)(kn0 + ty + r) * CC + c0 + tx];
    __syncthreads();
    #pragma unroll
    for (int r = 0; r < 32; r += 8)
        outp[(size_t)(c0 + ty + r) * KN + kn0 + tx] = tile[tx][ty + r];
}

// L2-normalize a strided row segment: in[row*in_ld + c], c in [0,cols) -> bf16 out[row*cols+c]
__global__ __launch_bounds__(256) void rownorm(const float* __restrict__ in, int in_ld,
                                               __hip_bfloat16* __restrict__ out, int cols)
{
    const int row = blockIdx.x;
    const float* p = in + (size_t)row * in_ld;
    float s = 0.f;
    for (int c = threadIdx.x; c < cols; c += 256) { float v = p[c]; s += v * v; }
    #pragma unroll
    for (int o = 32; o > 0; o >>= 1) s += __shfl_down(s, o, 64);
    __shared__ float red[4];
    if ((threadIdx.x & 63) == 0) red[threadIdx.x >> 6] = s;
    __syncthreads();
    const float tot = red[0] + red[1] + red[2] + red[3];
    const float inv = 1.f / fmaxf(sqrtf(tot), 1e-8f);
    for (int c = threadIdx.x; c < cols; c += 256)
        out[(size_t)row * cols + c] = (__hip_bfloat16)(p[c] * inv);
}

// Per kn-row: g[kn] = sum_c Ww[c]*Ekv[kn][CC+c]; EvT[kn][c] = (bf16)Ekv[kn][CC+c]
__global__ __launch_bounds__(256) void prep_gv(const float* __restrict__ Ekv,
                                               const float* __restrict__ Ww,
                                               float* __restrict__ g,
                                               __hip_bfloat16* __restrict__ EvT)
{
    const int kn = blockIdx.x;
    const float* p = Ekv + (size_t)kn * (2 * CC) + CC;
    float s = 0.f;
    for (int c = threadIdx.x; c < CC; c += 256) {
        const float v = p[c];
        s += Ww[c] * v;
        EvT[(size_t)kn * CC + c] = (__hip_bfloat16)v;
    }
    #pragma unroll
    for (int o = 32; o > 0; o >>= 1) s += __shfl_down(s, o, 64);
    __shared__ float red[4];
    if ((threadIdx.x & 63) == 0) red[threadIdx.x >> 6] = s;
    __syncthreads();
    if (threadIdx.x == 0) g[kn] = red[0] + red[1] + red[2] + red[3];
}

// per (b,k): softmax over 512, fw = sigmoid(dot(w,g)+bw), u = w*fw (bf16)
__global__ __launch_bounds__(64) void softmax_u(const float* __restrict__ sim,
                                                const float* __restrict__ g,
                                                const float* __restrict__ bw,
                                                __hip_bfloat16* __restrict__ u)
{
    const int bk = blockIdx.x;
    const int b = bk / KK, k = bk % KK;
    const float* sp = sim + (size_t)b * KN + k * NN;
    const float* gp = g + k * NN;
    const int lane = threadIdx.x;

    float vals[8];
    float m = -1e30f;
    #pragma unroll
    for (int j = 0; j < 8; ++j) { vals[j] = sp[lane + 64 * j]; m = fmaxf(m, vals[j]); }
    #pragma unroll
    for (int o = 32; o > 0; o >>= 1) m = fmaxf(m, __shfl_xor(m, o, 64));
    float sum = 0.f;
    #pragma unroll
    for (int j = 0; j < 8; ++j) { vals[j] = expf(vals[j] - m); sum += vals[j]; }
    #pragma unroll
    for (int o = 32; o > 0; o >>= 1) sum += __shfl_xor(sum, o, 64);
    const float inv = 1.f / sum;
    float dot = 0.f;
    #pragma unroll
    for (int j = 0; j < 8; ++j) { vals[j] *= inv; dot += vals[j] * gp[lane + 64 * j]; }
    #pragma unroll
    for (int o = 32; o > 0; o >>= 1) dot += __shfl_xor(dot, o, 64);
    const float fw = 1.f / (1.f + expf(-(dot + bw[0])));
    __hip_bfloat16* up = u + (size_t)b * KN + k * NN;
    #pragma unroll
    for (int j = 0; j < 8; ++j) up[lane + 64 * j] = (__hip_bfloat16)(vals[j] * fw);
}

// out[b][kk] = bout[kk] + sum_c Wout[kk][c]*relu(kv[b][CC+c]) + Wout[kk][CC+c]*relu(fE[b][c])
__global__ __launch_bounds__(256) void final_out(const float* __restrict__ kv,
                                                 const float* __restrict__ fE,
                                                 const float* __restrict__ Wout,
                                                 const float* __restrict__ bout,
                                                 float* __restrict__ out)
{
    const int b = blockIdx.x;
    const float* vp = kv + (size_t)b * (2 * CC) + CC;
    float acc[KK] = {0.f, 0.f, 0.f, 0.f, 0.f};
    for (int c = threadIdx.x; c < CC; c += 256) {
        const float rv = fmaxf(vp[c], 0.f);
        const float rf = fmaxf(fE[(size_t)b * CC + c], 0.f);
        #pragma unroll
        for (int kk = 0; kk < KK; ++kk)
            acc[kk] += Wout[kk * 2 * CC + c] * rv
                     + Wout[kk * 2 * CC + CC + c] * rf;
    }
    __shared__ float red[KK][4];
    const int lane = threadIdx.x & 63, wave = threadIdx.x >> 6;
    #pragma unroll
    for (int kk = 0; kk < KK; ++kk) {
        float s = acc[kk];
        #pragma unroll
        for (int o = 32; o > 0; o >>= 1) s += __shfl_down(s, o, 64);
        if (lane == 0) red[kk][wave] = s;
    }
    __syncthreads();
    if (threadIdx.x < KK) {
        float s = red[threadIdx.x][0] + red[threadIdx.x][1]
                + red[threadIdx.x][2] + red[threadIdx.x][3];
        out[(size_t)b * KK + threadIdx.x] = s + bout[threadIdx.x];
    }
}

extern "C" void kernel_launch(void* const* d_in, const int* in_sizes, int n_in,
                              void* d_out, int out_size, void* d_ws, size_t ws_size,
                              hipStream_t stream)
{
    const float* x    = (const float*)d_in[0];
    const float* stat = (const float*)d_in[1];
    const float* Wk   = (const float*)d_in[2];
    const float* bk   = (const float*)d_in[3];
    const float* Wv   = (const float*)d_in[4];
    const float* bv   = (const float*)d_in[5];
    const float* WEk  = (const float*)d_in[6];
    const float* bEk  = (const float*)d_in[7];
    const float* WEv  = (const float*)d_in[8];
    const float* bEv  = (const float*)d_in[9];
    const float* Ww   = (const float*)d_in[10];
    const float* bw   = (const float*)d_in[11];
    const float* Wout = (const float*)d_in[12];
    const float* bout = (const float*)d_in[13];
    float* out = (float*)d_out;
    char* ws = (char*)d_ws;

    // Linear workspace layout (~203 MB; ws is ~1 GB per the harness poison size).
    __hip_bfloat16* xb      = (__hip_bfloat16*)(ws + 0);          // [BB][CHIN]    16.78 MB
    __hip_bfloat16* Wkvb    = (__hip_bfloat16*)(ws + 16777216);   // [2CC][CHIN]    8.39 MB
    __hip_bfloat16* WEkvb   = (__hip_bfloat16*)(ws + 25165824);   // [2CC][CHIN]    8.39 MB
    __hip_bfloat16* staticT = (__hip_bfloat16*)(ws + 33554432);   // [KN][CHIN]    10.49 MB
    float*          Ekv     = (float*)(ws + 44040192);            // [KN][2CC]     20.97 MB
    __hip_bfloat16* EknT    = (__hip_bfloat16*)(ws + 65011712);   // [KN][CC]       5.24 MB
    __hip_bfloat16* EvT     = (__hip_bfloat16*)(ws + 70254592);   // [KN][CC]       5.24 MB
    __hip_bfloat16* EvC     = (__hip_bfloat16*)(ws + 75497472);   // [CC][KN]       5.24 MB
    float*          g       = (float*)(ws + 80740352);            // [KN]           10 KB
    float*          kv      = (float*)(ws + 80750592);            // [BB][2CC]     33.55 MB
    __hip_bfloat16* kn      = (__hip_bfloat16*)(ws + 114305024);  // [BB][CC]       8.39 MB
    float*          sim     = (float*)(ws + 122693632);           // [BB][KN]      41.94 MB
    __hip_bfloat16* u       = (__hip_bfloat16*)(ws + 164636672);  // [BB][KN]      20.97 MB
    float*          fE      = (float*)(ws + 185608192);           // [BB][CC]      16.78 MB
    float*          bkv     = (float*)(ws + 202385408);           // [2CC]          8 KB
    float*          bEkv    = (float*)(ws + 202393600);           // [2CC]          8 KB

    const int WN = CC * CHIN;  // elems per weight matrix

    // 0. input prep: casts + bias concats + static transpose
    cast_f32_bf16<<<WN / 1024, 256, 0, stream>>>(Wk,  Wkvb,       WN);
    cast_f32_bf16<<<WN / 1024, 256, 0, stream>>>(Wv,  Wkvb + WN,  WN);
    cast_f32_bf16<<<WN / 1024, 256, 0, stream>>>(WEk, WEkvb,      WN);
    cast_f32_bf16<<<WN / 1024, 256, 0, stream>>>(WEv, WEkvb + WN, WN);
    cast_xlast<<<dim3(CHIN / 1024, BB), 256, 0, stream>>>(x, xb);
    concat_bias<<<2 * CC / 256, 256, 0, stream>>>(bk, bv, bkv);
    concat_bias<<<2 * CC / 256, 256, 0, stream>>>(bEk, bEv, bEkv);
    transpose_static<<<dim3(CHIN / 32, NN / 32, KK), dim3(32, 8), 0, stream>>>(stat, staticT);

    // 1. Ekv[kn][0:CC]=Ek, [CC:2CC]=Ev  (one merged GEMM: M=KN, N=2CC, K=CHIN)
    gemm_abt<<<dim3(2 * CC / TN, KN / TM), 256, 0, stream>>>(
        staticT, CHIN, WEkvb, CHIN, Ekv, 2 * CC, KN, 2 * CC, CHIN, bEkv);
    // 2. EknT[kn][c] = Ek row-normalized (bf16)
    rownorm<<<KN, 256, 0, stream>>>(Ekv, 2 * CC, EknT, CC);
    // 3. g[kn] = Ww . Ev[kn,:]; EvT bf16
    prep_gv<<<KN, 256, 0, stream>>>(Ekv, Ww, g, EvT);
    // 4. EvC[c][kn] = EvT[kn][c]
    transpose_bf16<<<dim3(CC / 32, KN / 32), dim3(32, 8), 0, stream>>>(EvT, EvC);
    // 5. kv[b][0:CC]=k_pre, [CC:2CC]=v  (merged GEMM: M=BB, N=2CC, K=CHIN)
    gemm_abt<<<dim3(2 * CC / TN, BB / TM), 256, 0, stream>>>(
        xb, CHIN, Wkvb, CHIN, kv, 2 * CC, BB, 2 * CC, CHIN, bkv);
    // 6. kn = rownormalize(k_pre) (bf16)
    rownorm<<<BB, 256, 0, stream>>>(kv, 2 * CC, kn, CC);
    // 7. sim = kn @ EknT^T  (M=BB, N=KN, K=CC)
    gemm_abt<<<dim3(KN / TN, BB / TM), 256, 0, stream>>>(
        kn, CC, EknT, CC, sim, KN, BB, KN, CC, nullptr);
    // 8. softmax + fw -> u (bf16)
    softmax_u<<<BB * KK, 64, 0, stream>>>(sim, g, bw, u);
    // 9. fE = u @ EvC^T  (M=BB, N=CC, K=KN)
    gemm_abt<<<dim3(CC / TN, BB / TM), 256, 0, stream>>>(
        u, KN, EvC, KN, fE, CC, BB, CC, KN, nullptr);
    // 10. out = relu([v, fE]) @ Wout^T + bout (fp32 out)
    final_out<<<BB, 256, 0, stream>>>(kv, fE, Wout, bout, out);
}